// Round 14
// baseline (1224.213 us; speedup 1.0000x reference)
//
#include <hip/hip_runtime.h>
#include <hip/hip_bf16.h>
#include <math.h>

typedef __attribute__((ext_vector_type(8))) short short8;
typedef __attribute__((ext_vector_type(4))) short short4v;
typedef __attribute__((ext_vector_type(4))) float f32x4;

#define NH 12
#define DIM 384
#define HD 32

__device__ inline f32x4 mfma16(short8 a, short8 b, f32x4 c){
  return __builtin_amdgcn_mfma_f32_16x16x32_bf16(a, b, c, 0, 0, 0);
}

__device__ inline short fbits(float f){
  __hip_bfloat16 h = __float2bfloat16(f);
  short s; __builtin_memcpy(&s, &h, 2); return s;
}

__device__ inline float bf2f(short s){
  unsigned u = ((unsigned)(unsigned short)s) << 16;
  float f; __builtin_memcpy(&f, &u, 4); return f;
}

__device__ inline float wsum16(float v){
  #pragma unroll
  for (int off = 1; off < 16; off <<= 1) v += __shfl_xor(v, off);
  return v;
}
__device__ inline float wmax16(float v){
  #pragma unroll
  for (int off = 1; off < 16; off <<= 1) v = fmaxf(v, __shfl_xor(v, off));
  return v;
}

__device__ inline void gload16(const void* g, void* l){
  __builtin_amdgcn_global_load_lds(
      (const __attribute__((address_space(1))) unsigned int*)g,
      (__attribute__((address_space(3))) unsigned int*)l, 16, 0, 0);
}

// pack f32 weight [N][K] into MFMA B-fragment order
__global__ __launch_bounds__(256) void k_pack(
    const float* __restrict__ w, __hip_bfloat16* __restrict__ dst, int N, int K)
{
  int idx = blockIdx.x * 256 + threadIdx.x;
  int total = (K >> 5) * (N >> 4) * 64;
  if (idx >= total) return;
  int lane = idx & 63;
  int fn = idx >> 6;
  int nslots = N >> 4;
  int n = fn % nslots, kc = fn / nslots;
  const float* src = w + (size_t)(n * 16 + (lane & 15)) * K + kc * 32 + (lane >> 4) * 8;
  short8 o;
  #pragma unroll
  for (int j = 0; j < 8; j++) o[j] = fbits(src[j]);
  *(short8*)(dst + (size_t)idx * 8) = o;
}

// vectorized cast: 8 floats / thread
__global__ __launch_bounds__(256) void k_cast8(
    const float4* __restrict__ src, short4v* __restrict__ dst, int n8){
  int i = blockIdx.x * 256 + threadIdx.x;
  int stride = gridDim.x * 256;
  for (; i < n8; i += stride){
    float4 a = src[2 * i], b = src[2 * i + 1];
    short8 o;
    o[0] = fbits(a.x); o[1] = fbits(a.y); o[2] = fbits(a.z); o[3] = fbits(a.w);
    o[4] = fbits(b.x); o[5] = fbits(b.y); o[6] = fbits(b.z); o[7] = fbits(b.w);
    *(short8*)&dst[2 * i] = o;
  }
}

__device__ inline float cpbf(int a){
  float v = (float)a * (8.0f / 7.0f);
  float s = (v > 0.f) ? 1.f : ((v < 0.f) ? -1.f : 0.f);
  return s * log2f(fabsf(v) + 1.0f) * (1.0f / 3.0f);
}

__global__ __launch_bounds__(256) void k_cpb(
    const float* __restrict__ w1, const float* __restrict__ b1,
    const float* __restrict__ w2, float* __restrict__ hbias)
{
  __shared__ float hid[512];
  int t = blockIdx.x;  // 0..224
  float t0 = cpbf(t / 15 - 7), t1 = cpbf(t % 15 - 7);
  for (int j = threadIdx.x; j < 512; j += 256)
    hid[j] = fmaxf(w1[j * 2 + 0] * t0 + w1[j * 2 + 1] * t1 + b1[j], 0.f);
  __syncthreads();
  if (threadIdx.x < NH){
    float s = 0.f;
    for (int j = 0; j < 512; j++) s += hid[j] * w2[threadIdx.x * 512 + j];
    hbias[t * NH + threadIdx.x] = s;
  }
}

__global__ void k_bias16(const float* __restrict__ hbias,
                         const float* __restrict__ logit_scale,
                         float* __restrict__ bias16, float* __restrict__ scalev)
{
  int i = blockIdx.x * blockDim.x + threadIdx.x;
  if (i < NH) scalev[i] = expf(fminf(logit_scale[i], logf(100.0f)));
  if (i >= NH * 64 * 64) return;
  int h = i >> 12, r = (i >> 6) & 63, c = i & 63;
  int t = ((r >> 3) - (c >> 3) + 7) * 15 + ((r & 7) - (c & 7) + 7);
  float b = hbias[t * NH + h];
  bias16[i] = 16.0f / (1.0f + expf(-b));
}

// ---- qkv: A gathered via gload_lds, depth-4 prefetch (4 K-steps/barrier) --
// grid 9216 = 8 XCD x 128 mt x 9 nt; XCD-contiguous mt.
__global__ __launch_bounds__(256, 2) void k_qkv(
    const __hip_bfloat16* __restrict__ xb,     // bf16 natural order
    const __hip_bfloat16* __restrict__ wp,     // packed [12][72][64][8]
    const float* __restrict__ bias,
    const float* __restrict__ scalev,
    __hip_bfloat16* __restrict__ qb,
    __hip_bfloat16* __restrict__ kb,
    __hip_bfloat16* __restrict__ vT)           // [2048][12][32][64]
{
  __shared__ __attribute__((aligned(16))) char stage[8][8192];  // 64 KB
  const int tid = threadIdx.x, lane = tid & 63, wid = tid >> 6;
  const int colb = lane & 15, hi = lane >> 4;
  const int bid = blockIdx.x;
  const int xcd = bid & 7, idx = bid >> 3;
  const int mt = xcd * 128 + idx / 9;
  const int nt = idx % 9;
  const size_t row0 = (size_t)mt * 128;
  const int wm = wid >> 1, wn = wid & 1;

  // per-lane gather pointers for this wave's 2 A slots
  const __hip_bfloat16* sp[2];
  #pragma unroll
  for (int j = 0; j < 2; j++){
    int s = wid * 2 + j;
    int wr = (int)row0 + s * 16 + colb;
    int wiw = wr >> 6, t = wr & 63;
    int bb = wiw >> 6, wh = (wiw >> 3) & 7, ww = wiw & 7;
    int h = (wh * 8 + (t >> 3) + 4) & 63;
    int w2 = (ww * 8 + (t & 7) + 4) & 63;
    sp[j] = xb + ((size_t)(bb << 12) + (h << 6) + w2) * DIM + hi * 8;
  }
  auto stgA = [&](int sb, int kc){
    #pragma unroll
    for (int j = 0; j < 2; j++)
      gload16(sp[j] + kc * 32, &stage[sb][(wid * 2 + j) * 1024]);
  };

  const __hip_bfloat16* bbase = wp + ((size_t)(nt * 8 + wn * 4) * 64 + lane) * 8;
  auto loadB = [&](short8 (&bb)[4], int kc){
    #pragma unroll
    for (int ni = 0; ni < 4; ni++)
      bb[ni] = *(const short8*)(bbase + (size_t)kc * 36864 + ni * 512);
  };

  f32x4 acc[4][4];
  #pragma unroll
  for (int mi = 0; mi < 4; mi++)
    #pragma unroll
    for (int ni = 0; ni < 4; ni++) acc[mi][ni] = (f32x4)(0.f);

  auto compute = [&](int rb, short8 (&bc)[4]){
    short8 a[4];
    #pragma unroll
    for (int mi = 0; mi < 4; mi++)
      a[mi] = *(const short8*)&stage[rb][(wm * 4 + mi) * 1024 + lane * 16];
    #pragma unroll
    for (int mi = 0; mi < 4; mi++)
      #pragma unroll
      for (int ni = 0; ni < 4; ni++)
        acc[mi][ni] = mfma16(a[mi], bc[ni], acc[mi][ni]);
  };

  short8 bA[4], bB[4];
  stgA(0, 0); stgA(1, 1); stgA(2, 2); stgA(3, 3); loadB(bA, 0);
  __syncthreads();
  #pragma unroll
  for (int t = 0; t < 3; t++){
    int rb = (t & 1) * 4, sb = 4 - rb;
    if (t < 2){
      stgA(sb + 0, 4 * t + 4); stgA(sb + 1, 4 * t + 5);
      stgA(sb + 2, 4 * t + 6); stgA(sb + 3, 4 * t + 7);
    }
    loadB(bB, 4 * t + 1);
    compute(rb + 0, bA);
    loadB(bA, 4 * t + 2);
    compute(rb + 1, bB);
    loadB(bB, 4 * t + 3);
    compute(rb + 2, bA);
    if (t < 2) loadB(bA, 4 * t + 4);
    compute(rb + 3, bB);
    __syncthreads();
  }

  const int seg = nt / 3;
  const int segc0 = (nt % 3) * 128 + wn * 64;

  if (seg < 2){
    #pragma unroll
    for (int ni = 0; ni < 4; ni++){
      float fb = bias[seg * DIM + segc0 + ni * 16 + colb];
      #pragma unroll
      for (int mi = 0; mi < 4; mi++)
        #pragma unroll
        for (int rr = 0; rr < 4; rr++) acc[mi][ni][rr] += fb;
    }
    #pragma unroll
    for (int mi = 0; mi < 4; mi++)
      #pragma unroll
      for (int rr = 0; rr < 4; rr++)
        #pragma unroll
        for (int hh = 0; hh < 2; hh++){
          float s = acc[mi][2*hh][rr] * acc[mi][2*hh][rr]
                  + acc[mi][2*hh+1][rr] * acc[mi][2*hh+1][rr];
          s = wsum16(s);
          float inv = 1.0f / fmaxf(sqrtf(s), 1e-12f);
          if (seg == 0) inv *= scalev[(segc0 >> 5) + hh];
          acc[mi][2*hh][rr] *= inv;
          acc[mi][2*hh+1][rr] *= inv;
        }
    // wave-private LDS transpose -> vectorized 16B stores
    __hip_bfloat16* dst = (seg == 0) ? qb : kb;
    char* scr = (char*)stage + wid * 2304;    // 16 rows x 144B
    #pragma unroll
    for (int mi = 0; mi < 4; mi++){
      #pragma unroll
      for (int ni = 0; ni < 4; ni++)
        #pragma unroll
        for (int rr = 0; rr < 4; rr++)
          *(short*)(scr + (hi * 4 + rr) * 144 + (ni * 16 + colb) * 2) =
              fbits(acc[mi][ni][rr]);
      #pragma unroll
      for (int t = 0; t < 2; t++){
        int q = t * 64 + lane;
        int r = q >> 3, c8 = q & 7;
        short8 vv = *(const short8*)(scr + r * 144 + c8 * 16);
        *(short8*)(dst + (row0 + wm * 64 + mi * 16 + r) * DIM + segc0 + c8 * 8) = vv;
      }
    }
  } else {
    const int wi = mt * 2 + wm;
    #pragma unroll
    for (int ni = 0; ni < 4; ni++){
      float fb = bias[2 * DIM + segc0 + ni * 16 + colb];
      int head = (segc0 >> 5) + (ni >> 1);
      int d = (ni & 1) * 16 + colb;
      #pragma unroll
      for (int mi = 0; mi < 4; mi++){
        short4v pk;
        #pragma unroll
        for (int rr = 0; rr < 4; rr++) pk[rr] = fbits(acc[mi][ni][rr] + fb);
        *(short4v*)(vT + ((size_t)(wi * NH + head) * 32 + d) * 64
                       + mi * 16 + hi * 4) = pk;
      }
    }
  }
}

// ---- fused window attention + proj + LN1 + unshift + residual ------------
__global__ __launch_bounds__(256, 2) void k_winproj(
    const __hip_bfloat16* __restrict__ qb,
    const __hip_bfloat16* __restrict__ kb,
    const __hip_bfloat16* __restrict__ vT,     // [2048][12][32][64]
    const float* __restrict__ bias16,
    const __hip_bfloat16* __restrict__ projp,  // packed [12][24][64][8]
    const float* __restrict__ projb,
    const float* __restrict__ x,
    const float* __restrict__ g1, const float* __restrict__ b1v,
    __hip_bfloat16* __restrict__ yout)
{
  __shared__ __hip_bfloat16 Otile[64][392];    // 50,176 B (784B row, 16B-align)
  __shared__ __hip_bfloat16 P16[4][16][74];    // 9,472 B per-wave P mi-tile
  __shared__ int lbl[64];
  __shared__ float red1[64][4], red2[64][4];
  const int tid = threadIdx.x, lane = tid & 63, wid = tid >> 6;
  const int colb = lane & 15, hi = lane >> 4;
  const int wi = blockIdx.x;

  if (tid < 64){
    int wh = (wi >> 3) & 7, ww = wi & 7;
    int hp = wh * 8 + (tid >> 3), wp2 = ww * 8 + (tid & 7);
    int rh = (hp < 56) ? 0 : (hp < 60 ? 1 : 2);
    int rw = (wp2 < 56) ? 0 : (wp2 < 60 ? 1 : 2);
    lbl[tid] = rh * 3 + rw;
  }
  __syncthreads();

  int lblc[4], lblr[4][4];
  #pragma unroll
  for (int ni = 0; ni < 4; ni++) lblc[ni] = lbl[ni * 16 + colb];
  #pragma unroll
  for (int mi = 0; mi < 4; mi++)
    #pragma unroll
    for (int rr = 0; rr < 4; rr++) lblr[mi][rr] = lbl[mi * 16 + hi * 4 + rr];

  // ---------------- phase 1: attention, O -> Otile ----------------
  for (int h3 = 0; h3 < 3; h3++){
    const int head = wid * 3 + h3;
    short8 qf[4], kf[4];
    #pragma unroll
    for (int mi = 0; mi < 4; mi++)
      qf[mi] = *(const short8*)(qb + ((size_t)wi * 64 + mi * 16 + colb) * DIM
                                   + head * HD + hi * 8);
    #pragma unroll
    for (int ni = 0; ni < 4; ni++)
      kf[ni] = *(const short8*)(kb + ((size_t)wi * 64 + ni * 16 + colb) * DIM
                                   + head * HD + hi * 8);
    f32x4 s[4][4];
    #pragma unroll
    for (int mi = 0; mi < 4; mi++)
      #pragma unroll
      for (int ni = 0; ni < 4; ni++) s[mi][ni] = (f32x4)(0.f);
    #pragma unroll
    for (int ni = 0; ni < 4; ni++)
      #pragma unroll
      for (int mi = 0; mi < 4; mi++)
        s[mi][ni] = mfma16(qf[mi], kf[ni], s[mi][ni]);

    short8 vf[2][2];
    #pragma unroll
    for (int kc = 0; kc < 2; kc++)
      #pragma unroll
      for (int ni = 0; ni < 2; ni++)
        vf[kc][ni] = *(const short8*)(vT + ((size_t)(wi * NH + head) * 32
                                      + ni * 16 + colb) * 64 + kc * 32 + hi * 8);

    const float* bp = bias16 + (size_t)head * 4096;
    #pragma unroll
    for (int mi = 0; mi < 4; mi++){
      #pragma unroll
      for (int rr = 0; rr < 4; rr++){
        int row = mi * 16 + hi * 4 + rr;
        int li = lblr[mi][rr];
        float e[4]; float mx = -3e38f;
        #pragma unroll
        for (int ni = 0; ni < 4; ni++){
          float t = s[mi][ni][rr] + bp[row * 64 + ni * 16 + colb]
                    + ((lblc[ni] == li) ? 0.f : -100.f);
          e[ni] = t; mx = fmaxf(mx, t);
        }
        mx = wmax16(mx);
        float sm = 0.f;
        #pragma unroll
        for (int ni = 0; ni < 4; ni++){ e[ni] = __expf(e[ni] - mx); sm += e[ni]; }
        sm = wsum16(sm);
        float is = 1.0f / sm;
        #pragma unroll
        for (int ni = 0; ni < 4; ni++)
          P16[wid][hi * 4 + rr][ni * 16 + colb] = __float2bfloat16(e[ni] * is);
      }
      f32x4 o2[2];
      o2[0] = (f32x4)(0.f); o2[1] = (f32x4)(0.f);
      #pragma unroll
      for (int kc = 0; kc < 2; kc++){
        short8 pf = *(const short8*)&P16[wid][colb][kc * 32 + hi * 8];
        #pragma unroll
        for (int ni = 0; ni < 2; ni++)
          o2[ni] = mfma16(pf, vf[kc][ni], o2[ni]);
      }
      #pragma unroll
      for (int ni = 0; ni < 2; ni++)
        #pragma unroll
        for (int rr = 0; rr < 4; rr++)
          Otile[mi * 16 + hi * 4 + rr][head * HD + ni * 16 + colb] =
              __float2bfloat16(o2[ni][rr]);
    }
  }
  __syncthreads();

  // ---------------- phase 2: proj (zero barriers) ----------------
  f32x4 pacc[4][6];
  #pragma unroll
  for (int mi = 0; mi < 4; mi++)
    #pragma unroll
    for (int ni = 0; ni < 6; ni++) pacc[mi][ni] = (f32x4)(0.f);

  const __hip_bfloat16* pbase = projp + ((size_t)(wid * 6) * 64 + lane) * 8;
  auto loadPB = [&](short8 (&bb)[6], int kc){
    #pragma unroll
    for (int ni = 0; ni < 6; ni++)
      bb[ni] = *(const short8*)(pbase + (size_t)kc * 12288 + ni * 512);
  };
  short8 bA[6], bB[6];
  loadPB(bA, 0);
  auto pstep = [&](int kc, short8 (&bc)[6], short8 (&bn)[6]){
    if (kc < 11) loadPB(bn, kc + 1);
    short8 a[4];
    #pragma unroll
    for (int mi = 0; mi < 4; mi++)
      a[mi] = *(const short8*)&Otile[mi * 16 + colb][kc * 32 + hi * 8];
    #pragma unroll
    for (int mi = 0; mi < 4; mi++)
      #pragma unroll
      for (int ni = 0; ni < 6; ni++)
        pacc[mi][ni] = mfma16(a[mi], bc[ni], pacc[mi][ni]);
  };
  #pragma unroll
  for (int t = 0; t < 6; t++){
    pstep(2 * t, bA, bB);
    pstep(2 * t + 1, bB, bA);
  }

  // ---------------- LN1 partial sums ----------------
  float s1[4][4], s2[4][4];
  #pragma unroll
  for (int mi = 0; mi < 4; mi++)
    #pragma unroll
    for (int rr = 0; rr < 4; rr++){ s1[mi][rr] = 0.f; s2[mi][rr] = 0.f; }
  #pragma unroll
  for (int ni = 0; ni < 6; ni++){
    float pb = projb[wid * 96 + ni * 16 + colb];
    #pragma unroll
    for (int mi = 0; mi < 4; mi++)
      #pragma unroll
      for (int rr = 0; rr < 4; rr++){
        float v = pacc[mi][ni][rr] + pb;
        pacc[mi][ni][rr] = v;
        s1[mi][rr] += v; s2[mi][rr] += v * v;
      }
  }
  #pragma unroll
  for (int mi = 0; mi < 4; mi++)
    #pragma unroll
    for (int rr = 0; rr < 4; rr++){
      float a = wsum16(s1[mi][rr]);
      float b = wsum16(s2[mi][rr]);
      if (colb == 0){
        int row = mi * 16 + hi * 4 + rr;
        red1[row][wid] = a; red2[row][wid] = b;
      }
    }
  __syncthreads();   // red visible; all proj reads of Otile complete

  // LN -> write normalized values back into Otile
  #pragma unroll
  for (int mi = 0; mi < 4; mi++)
    #pragma unroll
    for (int rr = 0; rr < 4; rr++){
      int row = mi * 16 + hi * 4 + rr;
      float t1 = red1[row][0] + red1[row][1] + red1[row][2] + red1[row][3];
      float t2 = red2[row][0] + red2[row][1] + red2[row][2] + red2[row][3];
      float mean = t1 * (1.f / 384.f);
      float var  = t2 * (1.f / 384.f) - mean * mean;
      float inv  = rsqrtf(var + 1e-5f);
      #pragma unroll
      for (int ni = 0; ni < 6; ni++){
        int c = wid * 96 + ni * 16 + colb;
        Otile[row][c] = __float2bfloat16(
            (pacc[mi][ni][rr] - mean) * inv * g1[c] + b1v[c]);
      }
    }
  __syncthreads();

  // cooperative vectorized residual + store (8 elems per chunk)
  const int bbq = wi >> 6, whq = (wi >> 3) & 7, wwq = wi & 7;
  for (int q = tid; q < 3072; q += 256){
    int row = q / 48, cc = q - row * 48;
    int hq = (whq * 8 + (row >> 3) + 4) & 63;
    int wq = (wwq * 8 + (row & 7) + 4) & 63;
    size_t gpos = ((size_t)bbq << 12) + (hq << 6) + wq;
    const float* xp = x + gpos * DIM + cc * 8;
    float4 x0 = *(const float4*)xp;
    float4 x1 = *(const float4*)(xp + 4);
    short8 ov = *(const short8*)&Otile[row][cc * 8];
    short8 res;
    res[0] = fbits(x0.x + bf2f(ov[0]));
    res[1] = fbits(x0.y + bf2f(ov[1]));
    res[2] = fbits(x0.z + bf2f(ov[2]));
    res[3] = fbits(x0.w + bf2f(ov[3]));
    res[4] = fbits(x1.x + bf2f(ov[4]));
    res[5] = fbits(x1.y + bf2f(ov[5]));
    res[6] = fbits(x1.z + bf2f(ov[6]));
    res[7] = fbits(x1.w + bf2f(ov[7]));
    *(short8*)(yout + gpos * DIM + cc * 8) = res;
  }
}

// ---- fc1: 128x128 tiles, depth-4 prefetch, B packed-global, GELU -> h ----
// per chunk of 32768 rows: grid 3072 = 8 XCD x 32 mt x 12 nt.
__global__ __launch_bounds__(256, 2) void k_fc1(
    const __hip_bfloat16* __restrict__ y,      // [32768][384] chunk
    const __hip_bfloat16* __restrict__ wp,     // packed [12][96][64][8]
    const float* __restrict__ fc1b,
    __hip_bfloat16* __restrict__ h)            // [32768][1536] chunk
{
  __shared__ __attribute__((aligned(16))) char stage[8][8192];  // 64 KB
  const int tid = threadIdx.x, lane = tid & 63, wid = tid >> 6;
  const int colb = lane & 15, hi = lane >> 4;
  const int bid = blockIdx.x;
  const int xcd = bid & 7, idx = bid >> 3;
  const int mt = xcd * 32 + idx / 12, nt = idx % 12;
  const size_t row0 = (size_t)mt * 128;
  const int col0 = nt * 128;
  const int wm = wid >> 1, wn = wid & 1;

  auto stgA = [&](int sb, int kc){
    #pragma unroll
    for (int j = 0; j < 2; j++)
      gload16(y + (row0 + (wid * 2 + j) * 16 + colb) * DIM + kc * 32 + hi * 8,
              &stage[sb][(wid * 2 + j) * 1024]);
  };
  const __hip_bfloat16* bbase = wp + ((size_t)(nt * 8 + wn * 4) * 64 + lane) * 8;
  auto loadB = [&](short8 (&bb)[4], int kc){
    #pragma unroll
    for (int ni = 0; ni < 4; ni++)
      bb[ni] = *(const short8*)(bbase + (size_t)kc * 49152 + ni * 512);
  };

  f32x4 acc[4][4];
  #pragma unroll
  for (int mi = 0; mi < 4; mi++)
    #pragma unroll
    for (int ni = 0; ni < 4; ni++) acc[mi][ni] = (f32x4)(0.f);

  auto compute = [&](int rb, short8 (&bc)[4]){
    short8 a[4];
    #pragma unroll
    for (int mi = 0; mi < 4; mi++)
      a[mi] = *(const short8*)&stage[rb][(wm * 4 + mi) * 1024 + lane * 16];
    #pragma unroll
    for (int mi = 0; mi < 4; mi++)
      #pragma unroll
      for (int ni = 0; ni < 4; ni++)
        acc[mi][ni] = mfma16(a[mi], bc[ni], acc[mi][ni]);
  };

  short8 bA[4], bB[4];
  stgA(0, 0); stgA(1, 1); stgA(2, 2); stgA(3, 3); loadB(bA, 0);
  __syncthreads();
  #pragma unroll
  for (int t = 0; t < 3; t++){
    int rb = (t & 1) * 4, sb = 4 - rb;
    if (t < 2){
      stgA(sb + 0, 4 * t + 4); stgA(sb + 1, 4 * t + 5);
      stgA(sb + 2, 4 * t + 6); stgA(sb + 3, 4 * t + 7);
    }
    loadB(bB, 4 * t + 1);
    compute(rb + 0, bA);
    loadB(bA, 4 * t + 2);
    compute(rb + 1, bB);
    loadB(bB, 4 * t + 3);
    compute(rb + 2, bA);
    if (t < 2) loadB(bA, 4 * t + 4);
    compute(rb + 3, bB);
    __syncthreads();
  }

  // epilogue: bias + GELU -> wave-private LDS transpose -> 16B stores
  char* scr = (char*)stage + wid * 2304;    // 16 rows x 144B
  #pragma unroll
  for (int mi = 0; mi < 4; mi++){
    #pragma unroll
    for (int ni = 0; ni < 4; ni++){
      float fb = fc1b[col0 + wn * 64 + ni * 16 + colb];
      #pragma unroll
      for (int rr = 0; rr < 4; rr++){
        float v = acc[mi][ni][rr] + fb;
        float u = v * (1.0f + 0.044715f * v * v);
        float gl = v / (1.0f + __expf(-1.5957691216f * u));
        *(short*)(scr + (hi * 4 + rr) * 144 + (ni * 16 + colb) * 2) = fbits(gl);
      }
    }
    #pragma unroll
    for (int t = 0; t < 2; t++){
      int q = t * 64 + lane;
      int r = q >> 3, c8 = q & 7;
      short8 vv = *(const short8*)(scr + r * 144 + c8 * 16);
      *(short8*)(h + (row0 + wm * 64 + mi * 16 + r) * 1536
                 + col0 + wn * 64 + c8 * 8) = vv;
    }
  }
}

// ---- fc2: M=64 x N=384 x K=1536; depth-4 prefetch (4 K-steps/barrier) ----
// K = 48 steps = 12 iterations x 4.
__global__ __launch_bounds__(256, 2) void k_fc2(
    const __hip_bfloat16* __restrict__ h,      // [32768][1536] chunk
    const __hip_bfloat16* __restrict__ wp,     // packed [48][24][64][8]
    const float* __restrict__ fc2b,
    const __hip_bfloat16* __restrict__ y,      // chunk
    const float* __restrict__ g2, const float* __restrict__ b2v,
    float* __restrict__ out)                   // chunk
{
  __shared__ __attribute__((aligned(16))) char stage[8][4096];  // 32 KB
  __shared__ float red1[64][4], red2[64][4];
  const int tid = threadIdx.x, lane = tid & 63, wid = tid >> 6;
  const int colb = lane & 15, hi = lane >> 4;
  const size_t row0 = (size_t)blockIdx.x * 64;

  auto stgA = [&](int sb, int kc){
    gload16(h + (row0 + wid * 16 + colb) * 1536 + kc * 32 + hi * 8,
            &stage[sb][wid * 1024]);
  };
  const __hip_bfloat16* bbase = wp + ((size_t)(wid * 6) * 64 + lane) * 8;
  auto loadB = [&](short8 (&bb)[6], int kc){
    #pragma unroll
    for (int ni = 0; ni < 6; ni++)
      bb[ni] = *(const short8*)(bbase + (size_t)kc * 12288 + ni * 512);
  };

  f32x4 acc[4][6];
  #pragma unroll
  for (int mi = 0; mi < 4; mi++)
    #pragma unroll
    for (int ni = 0; ni < 6; ni++) acc[mi][ni] = (f32x4)(0.f);

  auto compute = [&](int rb, short8 (&bc)[6]){
    short8 a[4];
    #pragma unroll
    for (int mi = 0; mi < 4; mi++)
      a[mi] = *(const short8*)&stage[rb][mi * 1024 + lane * 16];
    #pragma unroll
    for (int mi = 0; mi < 4; mi++)
      #pragma unroll
      for (int ni = 0; ni < 6; ni++)
        acc[mi][ni] = mfma16(a[mi], bc[ni], acc[mi][ni]);
  };

  short8 bA[6], bB[6];
  stgA(0, 0); stgA(1, 1); stgA(2, 2); stgA(3, 3); loadB(bA, 0);
  __syncthreads();
  for (int t = 0; t < 12; t++){
    int rb = (t & 1) * 4, sb = 4 - rb;
    if (t < 11){
      stgA(sb + 0, 4 * t + 4); stgA(sb + 1, 4 * t + 5);
      stgA(sb + 2, 4 * t + 6); stgA(sb + 3, 4 * t + 7);
    }
    loadB(bB, 4 * t + 1);
    compute(rb + 0, bA);
    loadB(bA, 4 * t + 2);
    compute(rb + 1, bB);
    loadB(bB, 4 * t + 3);
    compute(rb + 2, bA);
    if (t < 11) loadB(bA, 4 * t + 4);
    compute(rb + 3, bB);
    __syncthreads();
  }

  float s1[4][4], s2[4][4];
  #pragma unroll
  for (int mi = 0; mi < 4; mi++)
    #pragma unroll
    for (int rr = 0; rr < 4; rr++){ s1[mi][rr] = 0.f; s2[mi][rr] = 0.f; }
  #pragma unroll
  for (int ni = 0; ni < 6; ni++){
    float fb = fc2b[wid * 96 + ni * 16 + colb];
    #pragma unroll
    for (int mi = 0; mi < 4; mi++)
      #pragma unroll
      for (int rr = 0; rr < 4; rr++){
        float v = acc[mi][ni][rr] + fb;
        acc[mi][ni][rr] = v;
        s1[mi][rr] += v; s2[mi][rr] += v * v;
      }
  }
  #pragma unroll
  for (int mi = 0; mi < 4; mi++)
    #pragma unroll
    for (int rr = 0; rr < 4; rr++){
      float a = wsum16(s1[mi][rr]);
      float b = wsum16(s2[mi][rr]);
      if (colb == 0){
        int row = mi * 16 + hi * 4 + rr;
        red1[row][wid] = a; red2[row][wid] = b;
      }
    }
  __syncthreads();

  #pragma unroll
  for (int mi = 0; mi < 4; mi++)
    #pragma unroll
    for (int rr = 0; rr < 4; rr++){
      int row = mi * 16 + hi * 4 + rr;
      float t1 = red1[row][0] + red1[row][1] + red1[row][2] + red1[row][3];
      float t2 = red2[row][0] + red2[row][1] + red2[row][2] + red2[row][3];
      float mean = t1 * (1.f / 384.f);
      float var  = t2 * (1.f / 384.f) - mean * mean;
      float inv  = rsqrtf(var + 1e-5f);
      size_t grow = row0 + row;
      const __hip_bfloat16* yp = y + grow * DIM;
      float* op = out + grow * DIM;
      #pragma unroll
      for (int ni = 0; ni < 6; ni++){
        int c = wid * 96 + ni * 16 + colb;
        float ln = (acc[mi][ni][rr] - mean) * inv * g2[c] + b2v[c];
        op[c] = bf2f(*(const short*)(yp + c)) + ln;
      }
    }
}

extern "C" void kernel_launch(void* const* d_in, const int* in_sizes, int n_in,
                              void* d_out, int out_size, void* d_ws, size_t ws_size,
                              hipStream_t stream)
{
  (void)in_sizes; (void)n_in; (void)out_size; (void)ws_size;
  const float* x    = (const float*)d_in[0];
  const float* qkvw_f = (const float*)d_in[3];
  const float* qkvb = (const float*)d_in[4];
  const float* lsc  = (const float*)d_in[5];
  const float* cw1  = (const float*)d_in[6];
  const float* cb1  = (const float*)d_in[7];
  const float* cw2  = (const float*)d_in[8];
  const float* pw   = (const float*)d_in[9];
  const float* pb   = (const float*)d_in[10];
  const float* g1   = (const float*)d_in[11];
  const float* b1   = (const float*)d_in[12];
  const float* g2   = (const float*)d_in[13];
  const float* b2   = (const float*)d_in[14];
  const float* f1w  = (const float*)d_in[15];
  const float* f1b  = (const float*)d_in[16];
  const float* f2w  = (const float*)d_in[17];
  const float* f2b  = (const float*)d_in[18];

  char* ws = (char*)d_ws;
  size_t off = 0;
  auto alloc = [&](size_t bytes) -> char* {
    char* p = ws + off;
    off += (bytes + 255) & ~(size_t)255;
    return p;
  };
  __hip_bfloat16* qkvp = (__hip_bfloat16*)alloc((size_t)12 * 72 * 512 * 2);
  __hip_bfloat16* projp= (__hip_bfloat16*)alloc((size_t)12 * 24 * 512 * 2);
  __hip_bfloat16* fc1p = (__hip_bfloat16*)alloc((size_t)12 * 96 * 512 * 2);
  __hip_bfloat16* fc2p = (__hip_bfloat16*)alloc((size_t)48 * 24 * 512 * 2);
  float* scalev = (float*)alloc(NH * 4);
  float* hbias  = (float*)alloc(225 * NH * 4);
  float* bias16 = (float*)alloc((size_t)NH * 64 * 64 * 4);
  __hip_bfloat16* yb    = (__hip_bfloat16*)alloc((size_t)131072 * DIM * 2);
  __hip_bfloat16* xbb   = (__hip_bfloat16*)alloc((size_t)131072 * DIM * 2);
  __hip_bfloat16* qbuf  = (__hip_bfloat16*)alloc((size_t)131072 * DIM * 2);
  __hip_bfloat16* kbuf  = (__hip_bfloat16*)alloc((size_t)131072 * DIM * 2);
  __hip_bfloat16* vTbuf = (__hip_bfloat16*)alloc((size_t)131072 * DIM * 2);
  // h [131072][1536] bf16 = 402,653,184 B overlays xbb+qbuf+kbuf+vTbuf
  __hip_bfloat16* hbuf  = xbb;

  k_pack<<<216, 256, 0, stream>>>(qkvw_f, qkvp, 1152, 384);
  k_pack<<<72, 256, 0, stream>>>(pw, projp, 384, 384);
  k_pack<<<288, 256, 0, stream>>>(f1w, fc1p, 1536, 384);
  k_pack<<<288, 256, 0, stream>>>(f2w, fc2p, 384, 1536);
  k_cpb<<<225, 256, 0, stream>>>(cw1, cb1, cw2, hbias);
  k_bias16<<<192, 256, 0, stream>>>(hbias, lsc, bias16, scalev);

  k_cast8<<<2048, 256, 0, stream>>>((const float4*)x, (short4v*)xbb,
                                    131072 * DIM / 8);
  k_qkv<<<9216, 256, 0, stream>>>(xbb, qkvp, qkvb, scalev, qbuf, kbuf, vTbuf);
  k_winproj<<<2048, 256, 0, stream>>>(qbuf, kbuf, vTbuf, bias16, projp, pb,
                                      x, g1, b1, yb);

  // MLP in 4 chunks of 32768 rows so the h chunk (100.7 MB) stays L3-resident
  for (int c = 0; c < 4; c++){
    size_t ro = (size_t)c * 32768;
    k_fc1<<<3072, 256, 0, stream>>>(yb + ro * DIM, fc1p, f1b,
                                    hbuf + ro * 1536);
    k_fc2<<<512, 256, 0, stream>>>(hbuf + ro * 1536, fc2p, f2b, yb + ro * DIM,
                                   g2, b2, (float*)d_out + ro * DIM);
  }
}

// Round 15
// 1055.588 us; speedup vs baseline: 1.1597x; 1.1597x over previous
//
#include <hip/hip_runtime.h>
#include <hip/hip_bf16.h>
#include <math.h>

typedef __attribute__((ext_vector_type(8))) short short8;
typedef __attribute__((ext_vector_type(4))) short short4v;
typedef __attribute__((ext_vector_type(4))) float f32x4;

#define NH 12
#define DIM 384
#define HD 32

__device__ inline f32x4 mfma16(short8 a, short8 b, f32x4 c){
  return __builtin_amdgcn_mfma_f32_16x16x32_bf16(a, b, c, 0, 0, 0);
}

__device__ inline short fbits(float f){
  __hip_bfloat16 h = __float2bfloat16(f);
  short s; __builtin_memcpy(&s, &h, 2); return s;
}

__device__ inline float bf2f(short s){
  unsigned u = ((unsigned)(unsigned short)s) << 16;
  float f; __builtin_memcpy(&f, &u, 4); return f;
}

__device__ inline float wsum16(float v){
  #pragma unroll
  for (int off = 1; off < 16; off <<= 1) v += __shfl_xor(v, off);
  return v;
}
__device__ inline float wmax16(float v){
  #pragma unroll
  for (int off = 1; off < 16; off <<= 1) v = fmaxf(v, __shfl_xor(v, off));
  return v;
}

__device__ inline void gload16(const void* g, void* l){
  __builtin_amdgcn_global_load_lds(
      (const __attribute__((address_space(1))) unsigned int*)g,
      (__attribute__((address_space(3))) unsigned int*)l, 16, 0, 0);
}

// pack f32 weight [N][K] into MFMA B-fragment order
__global__ __launch_bounds__(256) void k_pack(
    const float* __restrict__ w, __hip_bfloat16* __restrict__ dst, int N, int K)
{
  int idx = blockIdx.x * 256 + threadIdx.x;
  int total = (K >> 5) * (N >> 4) * 64;
  if (idx >= total) return;
  int lane = idx & 63;
  int fn = idx >> 6;
  int nslots = N >> 4;
  int n = fn % nslots, kc = fn / nslots;
  const float* src = w + (size_t)(n * 16 + (lane & 15)) * K + kc * 32 + (lane >> 4) * 8;
  short8 o;
  #pragma unroll
  for (int j = 0; j < 8; j++) o[j] = fbits(src[j]);
  *(short8*)(dst + (size_t)idx * 8) = o;
}

// vectorized cast: 8 floats / thread
__global__ __launch_bounds__(256) void k_cast8(
    const float4* __restrict__ src, short4v* __restrict__ dst, int n8){
  int i = blockIdx.x * 256 + threadIdx.x;
  int stride = gridDim.x * 256;
  for (; i < n8; i += stride){
    float4 a = src[2 * i], b = src[2 * i + 1];
    short8 o;
    o[0] = fbits(a.x); o[1] = fbits(a.y); o[2] = fbits(a.z); o[3] = fbits(a.w);
    o[4] = fbits(b.x); o[5] = fbits(b.y); o[6] = fbits(b.z); o[7] = fbits(b.w);
    *(short8*)&dst[2 * i] = o;
  }
}

__device__ inline float cpbf(int a){
  float v = (float)a * (8.0f / 7.0f);
  float s = (v > 0.f) ? 1.f : ((v < 0.f) ? -1.f : 0.f);
  return s * log2f(fabsf(v) + 1.0f) * (1.0f / 3.0f);
}

__global__ __launch_bounds__(256) void k_cpb(
    const float* __restrict__ w1, const float* __restrict__ b1,
    const float* __restrict__ w2, float* __restrict__ hbias)
{
  __shared__ float hid[512];
  int t = blockIdx.x;  // 0..224
  float t0 = cpbf(t / 15 - 7), t1 = cpbf(t % 15 - 7);
  for (int j = threadIdx.x; j < 512; j += 256)
    hid[j] = fmaxf(w1[j * 2 + 0] * t0 + w1[j * 2 + 1] * t1 + b1[j], 0.f);
  __syncthreads();
  if (threadIdx.x < NH){
    float s = 0.f;
    for (int j = 0; j < 512; j++) s += hid[j] * w2[threadIdx.x * 512 + j];
    hbias[t * NH + threadIdx.x] = s;
  }
}

__global__ void k_bias16(const float* __restrict__ hbias,
                         const float* __restrict__ logit_scale,
                         float* __restrict__ bias16, float* __restrict__ scalev)
{
  int i = blockIdx.x * blockDim.x + threadIdx.x;
  if (i < NH) scalev[i] = expf(fminf(logit_scale[i], logf(100.0f)));
  if (i >= NH * 64 * 64) return;
  int h = i >> 12, r = (i >> 6) & 63, c = i & 63;
  int t = ((r >> 3) - (c >> 3) + 7) * 15 + ((r & 7) - (c & 7) + 7);
  float b = hbias[t * NH + h];
  bias16[i] = 16.0f / (1.0f + expf(-b));
}

// ---- qkv: A gathered via gload_lds (2 K-steps/barrier), B packed->reg ----
// grid 9216 = 8 XCD x 128 mt x 9 nt; XCD-contiguous mt.
__global__ __launch_bounds__(256, 4) void k_qkv(
    const __hip_bfloat16* __restrict__ xb,     // bf16 natural order
    const __hip_bfloat16* __restrict__ wp,     // packed [12][72][64][8]
    const float* __restrict__ bias,
    const float* __restrict__ scalev,
    __hip_bfloat16* __restrict__ qb,
    __hip_bfloat16* __restrict__ kb,
    __hip_bfloat16* __restrict__ vT)           // [2048][12][32][64]
{
  __shared__ __attribute__((aligned(16))) char stage[4][8192];  // 32 KB
  const int tid = threadIdx.x, lane = tid & 63, wid = tid >> 6;
  const int colb = lane & 15, hi = lane >> 4;
  const int bid = blockIdx.x;
  const int xcd = bid & 7, idx = bid >> 3;
  const int mt = xcd * 128 + idx / 9;
  const int nt = idx % 9;
  const size_t row0 = (size_t)mt * 128;
  const int wm = wid >> 1, wn = wid & 1;

  // per-lane gather pointers for this wave's 2 A slots
  const __hip_bfloat16* sp[2];
  #pragma unroll
  for (int j = 0; j < 2; j++){
    int s = wid * 2 + j;
    int wr = (int)row0 + s * 16 + colb;
    int wiw = wr >> 6, t = wr & 63;
    int bb = wiw >> 6, wh = (wiw >> 3) & 7, ww = wiw & 7;
    int h = (wh * 8 + (t >> 3) + 4) & 63;
    int w2 = (ww * 8 + (t & 7) + 4) & 63;
    sp[j] = xb + ((size_t)(bb << 12) + (h << 6) + w2) * DIM + hi * 8;
  }
  auto stgA = [&](int sb, int kc){
    #pragma unroll
    for (int j = 0; j < 2; j++)
      gload16(sp[j] + kc * 32, &stage[sb][(wid * 2 + j) * 1024]);
  };

  const __hip_bfloat16* bbase = wp + ((size_t)(nt * 8 + wn * 4) * 64 + lane) * 8;
  auto loadB = [&](short8 (&bb)[4], int kc){
    #pragma unroll
    for (int ni = 0; ni < 4; ni++)
      bb[ni] = *(const short8*)(bbase + (size_t)kc * 36864 + ni * 512);
  };

  f32x4 acc[4][4];
  #pragma unroll
  for (int mi = 0; mi < 4; mi++)
    #pragma unroll
    for (int ni = 0; ni < 4; ni++) acc[mi][ni] = (f32x4)(0.f);

  auto compute = [&](int rb, short8 (&bc)[4]){
    short8 a[4];
    #pragma unroll
    for (int mi = 0; mi < 4; mi++)
      a[mi] = *(const short8*)&stage[rb][(wm * 4 + mi) * 1024 + lane * 16];
    #pragma unroll
    for (int mi = 0; mi < 4; mi++)
      #pragma unroll
      for (int ni = 0; ni < 4; ni++)
        acc[mi][ni] = mfma16(a[mi], bc[ni], acc[mi][ni]);
  };

  short8 bA[4], bB[4];
  stgA(0, 0); stgA(1, 1); loadB(bA, 0);
  __syncthreads();
  #pragma unroll
  for (int t = 0; t < 6; t++){
    int rb = (t & 1) * 2, sb = 2 - rb;
    if (t < 5){ stgA(sb, 2 * t + 2); stgA(sb + 1, 2 * t + 3); }
    loadB(bB, 2 * t + 1);
    compute(rb, bA);
    if (t < 5) loadB(bA, 2 * t + 2);
    compute(rb + 1, bB);
    __syncthreads();
  }

  const int seg = nt / 3;
  const int segc0 = (nt % 3) * 128 + wn * 64;

  if (seg < 2){
    #pragma unroll
    for (int ni = 0; ni < 4; ni++){
      float fb = bias[seg * DIM + segc0 + ni * 16 + colb];
      #pragma unroll
      for (int mi = 0; mi < 4; mi++)
        #pragma unroll
        for (int rr = 0; rr < 4; rr++) acc[mi][ni][rr] += fb;
    }
    #pragma unroll
    for (int mi = 0; mi < 4; mi++)
      #pragma unroll
      for (int rr = 0; rr < 4; rr++)
        #pragma unroll
        for (int hh = 0; hh < 2; hh++){
          float s = acc[mi][2*hh][rr] * acc[mi][2*hh][rr]
                  + acc[mi][2*hh+1][rr] * acc[mi][2*hh+1][rr];
          s = wsum16(s);
          float inv = 1.0f / fmaxf(sqrtf(s), 1e-12f);
          if (seg == 0) inv *= scalev[(segc0 >> 5) + hh];
          acc[mi][2*hh][rr] *= inv;
          acc[mi][2*hh+1][rr] *= inv;
        }
    // wave-private LDS transpose -> vectorized 16B stores
    __hip_bfloat16* dst = (seg == 0) ? qb : kb;
    char* scr = (char*)stage + wid * 2304;    // 16 rows x 144B
    #pragma unroll
    for (int mi = 0; mi < 4; mi++){
      #pragma unroll
      for (int ni = 0; ni < 4; ni++)
        #pragma unroll
        for (int rr = 0; rr < 4; rr++)
          *(short*)(scr + (hi * 4 + rr) * 144 + (ni * 16 + colb) * 2) =
              fbits(acc[mi][ni][rr]);
      #pragma unroll
      for (int t = 0; t < 2; t++){
        int q = t * 64 + lane;
        int r = q >> 3, c8 = q & 7;
        short8 vv = *(const short8*)(scr + r * 144 + c8 * 16);
        *(short8*)(dst + (row0 + wm * 64 + mi * 16 + r) * DIM + segc0 + c8 * 8) = vv;
      }
    }
  } else {
    const int wi = mt * 2 + wm;
    #pragma unroll
    for (int ni = 0; ni < 4; ni++){
      float fb = bias[2 * DIM + segc0 + ni * 16 + colb];
      int head = (segc0 >> 5) + (ni >> 1);
      int d = (ni & 1) * 16 + colb;
      #pragma unroll
      for (int mi = 0; mi < 4; mi++){
        short4v pk;
        #pragma unroll
        for (int rr = 0; rr < 4; rr++) pk[rr] = fbits(acc[mi][ni][rr] + fb);
        *(short4v*)(vT + ((size_t)(wi * NH + head) * 32 + d) * 64
                       + mi * 16 + hi * 4) = pk;
      }
    }
  }
}

// ---- fused window attention + proj + LN1 + unshift + residual ------------
__global__ __launch_bounds__(256, 2) void k_winproj(
    const __hip_bfloat16* __restrict__ qb,
    const __hip_bfloat16* __restrict__ kb,
    const __hip_bfloat16* __restrict__ vT,     // [2048][12][32][64]
    const float* __restrict__ bias16,
    const __hip_bfloat16* __restrict__ projp,  // packed [12][24][64][8]
    const float* __restrict__ projb,
    const float* __restrict__ x,
    const float* __restrict__ g1, const float* __restrict__ b1v,
    __hip_bfloat16* __restrict__ yout)
{
  __shared__ __hip_bfloat16 Otile[64][392];    // 50,176 B (784B row, 16B-align)
  __shared__ __hip_bfloat16 P16[4][16][74];    // 9,472 B per-wave P mi-tile
  __shared__ int lbl[64];
  __shared__ float red1[64][4], red2[64][4];
  const int tid = threadIdx.x, lane = tid & 63, wid = tid >> 6;
  const int colb = lane & 15, hi = lane >> 4;
  const int wi = blockIdx.x;

  if (tid < 64){
    int wh = (wi >> 3) & 7, ww = wi & 7;
    int hp = wh * 8 + (tid >> 3), wp2 = ww * 8 + (tid & 7);
    int rh = (hp < 56) ? 0 : (hp < 60 ? 1 : 2);
    int rw = (wp2 < 56) ? 0 : (wp2 < 60 ? 1 : 2);
    lbl[tid] = rh * 3 + rw;
  }
  __syncthreads();

  int lblc[4], lblr[4][4];
  #pragma unroll
  for (int ni = 0; ni < 4; ni++) lblc[ni] = lbl[ni * 16 + colb];
  #pragma unroll
  for (int mi = 0; mi < 4; mi++)
    #pragma unroll
    for (int rr = 0; rr < 4; rr++) lblr[mi][rr] = lbl[mi * 16 + hi * 4 + rr];

  // ---------------- phase 1: attention, O -> Otile ----------------
  for (int h3 = 0; h3 < 3; h3++){
    const int head = wid * 3 + h3;
    short8 qf[4], kf[4];
    #pragma unroll
    for (int mi = 0; mi < 4; mi++)
      qf[mi] = *(const short8*)(qb + ((size_t)wi * 64 + mi * 16 + colb) * DIM
                                   + head * HD + hi * 8);
    #pragma unroll
    for (int ni = 0; ni < 4; ni++)
      kf[ni] = *(const short8*)(kb + ((size_t)wi * 64 + ni * 16 + colb) * DIM
                                   + head * HD + hi * 8);
    f32x4 s[4][4];
    #pragma unroll
    for (int mi = 0; mi < 4; mi++)
      #pragma unroll
      for (int ni = 0; ni < 4; ni++) s[mi][ni] = (f32x4)(0.f);
    #pragma unroll
    for (int ni = 0; ni < 4; ni++)
      #pragma unroll
      for (int mi = 0; mi < 4; mi++)
        s[mi][ni] = mfma16(qf[mi], kf[ni], s[mi][ni]);

    short8 vf[2][2];
    #pragma unroll
    for (int kc = 0; kc < 2; kc++)
      #pragma unroll
      for (int ni = 0; ni < 2; ni++)
        vf[kc][ni] = *(const short8*)(vT + ((size_t)(wi * NH + head) * 32
                                      + ni * 16 + colb) * 64 + kc * 32 + hi * 8);

    const float* bp = bias16 + (size_t)head * 4096;
    #pragma unroll
    for (int mi = 0; mi < 4; mi++){
      #pragma unroll
      for (int rr = 0; rr < 4; rr++){
        int row = mi * 16 + hi * 4 + rr;
        int li = lblr[mi][rr];
        float e[4]; float mx = -3e38f;
        #pragma unroll
        for (int ni = 0; ni < 4; ni++){
          float t = s[mi][ni][rr] + bp[row * 64 + ni * 16 + colb]
                    + ((lblc[ni] == li) ? 0.f : -100.f);
          e[ni] = t; mx = fmaxf(mx, t);
        }
        mx = wmax16(mx);
        float sm = 0.f;
        #pragma unroll
        for (int ni = 0; ni < 4; ni++){ e[ni] = __expf(e[ni] - mx); sm += e[ni]; }
        sm = wsum16(sm);
        float is = 1.0f / sm;
        #pragma unroll
        for (int ni = 0; ni < 4; ni++)
          P16[wid][hi * 4 + rr][ni * 16 + colb] = __float2bfloat16(e[ni] * is);
      }
      f32x4 o2[2];
      o2[0] = (f32x4)(0.f); o2[1] = (f32x4)(0.f);
      #pragma unroll
      for (int kc = 0; kc < 2; kc++){
        short8 pf = *(const short8*)&P16[wid][colb][kc * 32 + hi * 8];
        #pragma unroll
        for (int ni = 0; ni < 2; ni++)
          o2[ni] = mfma16(pf, vf[kc][ni], o2[ni]);
      }
      #pragma unroll
      for (int ni = 0; ni < 2; ni++)
        #pragma unroll
        for (int rr = 0; rr < 4; rr++)
          Otile[mi * 16 + hi * 4 + rr][head * HD + ni * 16 + colb] =
              __float2bfloat16(o2[ni][rr]);
    }
  }
  __syncthreads();

  // ---------------- phase 2: proj (zero barriers) ----------------
  f32x4 pacc[4][6];
  #pragma unroll
  for (int mi = 0; mi < 4; mi++)
    #pragma unroll
    for (int ni = 0; ni < 6; ni++) pacc[mi][ni] = (f32x4)(0.f);

  const __hip_bfloat16* pbase = projp + ((size_t)(wid * 6) * 64 + lane) * 8;
  auto loadPB = [&](short8 (&bb)[6], int kc){
    #pragma unroll
    for (int ni = 0; ni < 6; ni++)
      bb[ni] = *(const short8*)(pbase + (size_t)kc * 12288 + ni * 512);
  };
  short8 bA[6], bB[6];
  loadPB(bA, 0);
  auto pstep = [&](int kc, short8 (&bc)[6], short8 (&bn)[6]){
    if (kc < 11) loadPB(bn, kc + 1);
    short8 a[4];
    #pragma unroll
    for (int mi = 0; mi < 4; mi++)
      a[mi] = *(const short8*)&Otile[mi * 16 + colb][kc * 32 + hi * 8];
    #pragma unroll
    for (int mi = 0; mi < 4; mi++)
      #pragma unroll
      for (int ni = 0; ni < 6; ni++)
        pacc[mi][ni] = mfma16(a[mi], bc[ni], pacc[mi][ni]);
  };
  #pragma unroll
  for (int t = 0; t < 6; t++){
    pstep(2 * t, bA, bB);
    pstep(2 * t + 1, bB, bA);
  }

  // ---------------- LN1 partial sums ----------------
  float s1[4][4], s2[4][4];
  #pragma unroll
  for (int mi = 0; mi < 4; mi++)
    #pragma unroll
    for (int rr = 0; rr < 4; rr++){ s1[mi][rr] = 0.f; s2[mi][rr] = 0.f; }
  #pragma unroll
  for (int ni = 0; ni < 6; ni++){
    float pb = projb[wid * 96 + ni * 16 + colb];
    #pragma unroll
    for (int mi = 0; mi < 4; mi++)
      #pragma unroll
      for (int rr = 0; rr < 4; rr++){
        float v = pacc[mi][ni][rr] + pb;
        pacc[mi][ni][rr] = v;
        s1[mi][rr] += v; s2[mi][rr] += v * v;
      }
  }
  #pragma unroll
  for (int mi = 0; mi < 4; mi++)
    #pragma unroll
    for (int rr = 0; rr < 4; rr++){
      float a = wsum16(s1[mi][rr]);
      float b = wsum16(s2[mi][rr]);
      if (colb == 0){
        int row = mi * 16 + hi * 4 + rr;
        red1[row][wid] = a; red2[row][wid] = b;
      }
    }
  __syncthreads();   // red visible; all proj reads of Otile complete

  // LN -> write normalized values back into Otile
  #pragma unroll
  for (int mi = 0; mi < 4; mi++)
    #pragma unroll
    for (int rr = 0; rr < 4; rr++){
      int row = mi * 16 + hi * 4 + rr;
      float t1 = red1[row][0] + red1[row][1] + red1[row][2] + red1[row][3];
      float t2 = red2[row][0] + red2[row][1] + red2[row][2] + red2[row][3];
      float mean = t1 * (1.f / 384.f);
      float var  = t2 * (1.f / 384.f) - mean * mean;
      float inv  = rsqrtf(var + 1e-5f);
      #pragma unroll
      for (int ni = 0; ni < 6; ni++){
        int c = wid * 96 + ni * 16 + colb;
        Otile[row][c] = __float2bfloat16(
            (pacc[mi][ni][rr] - mean) * inv * g1[c] + b1v[c]);
      }
    }
  __syncthreads();

  // cooperative vectorized residual + store (8 elems per chunk)
  const int bbq = wi >> 6, whq = (wi >> 3) & 7, wwq = wi & 7;
  for (int q = tid; q < 3072; q += 256){
    int row = q / 48, cc = q - row * 48;
    int hq = (whq * 8 + (row >> 3) + 4) & 63;
    int wq = (wwq * 8 + (row & 7) + 4) & 63;
    size_t gpos = ((size_t)bbq << 12) + (hq << 6) + wq;
    const float* xp = x + gpos * DIM + cc * 8;
    float4 x0 = *(const float4*)xp;
    float4 x1 = *(const float4*)(xp + 4);
    short8 ov = *(const short8*)&Otile[row][cc * 8];
    short8 res;
    res[0] = fbits(x0.x + bf2f(ov[0]));
    res[1] = fbits(x0.y + bf2f(ov[1]));
    res[2] = fbits(x0.z + bf2f(ov[2]));
    res[3] = fbits(x0.w + bf2f(ov[3]));
    res[4] = fbits(x1.x + bf2f(ov[4]));
    res[5] = fbits(x1.y + bf2f(ov[5]));
    res[6] = fbits(x1.z + bf2f(ov[6]));
    res[7] = fbits(x1.w + bf2f(ov[7]));
    *(short8*)(yout + gpos * DIM + cc * 8) = res;
  }
}

// ---- fc1: 128x128 tiles, 2 K-steps/barrier, B packed-global, GELU -> h ---
// grid 12288 = 8 XCD x 128 mt x 12 nt; XCD-contiguous mt.
__global__ __launch_bounds__(256, 4) void k_fc1(
    const __hip_bfloat16* __restrict__ y,      // [131072][384]
    const __hip_bfloat16* __restrict__ wp,     // packed [12][96][64][8]
    const float* __restrict__ fc1b,
    __hip_bfloat16* __restrict__ h)            // [131072][1536]
{
  __shared__ __attribute__((aligned(16))) char stage[4][8192];
  const int tid = threadIdx.x, lane = tid & 63, wid = tid >> 6;
  const int colb = lane & 15, hi = lane >> 4;
  const int bid = blockIdx.x;
  const int xcd = bid & 7, idx = bid >> 3;
  const int mt = xcd * 128 + idx / 12, nt = idx % 12;
  const size_t row0 = (size_t)mt * 128;
  const int col0 = nt * 128;
  const int wm = wid >> 1, wn = wid & 1;

  auto stgA = [&](int sb, int kc){
    #pragma unroll
    for (int j = 0; j < 2; j++)
      gload16(y + (row0 + (wid * 2 + j) * 16 + colb) * DIM + kc * 32 + hi * 8,
              &stage[sb][(wid * 2 + j) * 1024]);
  };
  const __hip_bfloat16* bbase = wp + ((size_t)(nt * 8 + wn * 4) * 64 + lane) * 8;
  auto loadB = [&](short8 (&bb)[4], int kc){
    #pragma unroll
    for (int ni = 0; ni < 4; ni++)
      bb[ni] = *(const short8*)(bbase + (size_t)kc * 49152 + ni * 512);
  };

  f32x4 acc[4][4];
  #pragma unroll
  for (int mi = 0; mi < 4; mi++)
    #pragma unroll
    for (int ni = 0; ni < 4; ni++) acc[mi][ni] = (f32x4)(0.f);

  auto compute = [&](int rb, short8 (&bc)[4]){
    short8 a[4];
    #pragma unroll
    for (int mi = 0; mi < 4; mi++)
      a[mi] = *(const short8*)&stage[rb][(wm * 4 + mi) * 1024 + lane * 16];
    #pragma unroll
    for (int mi = 0; mi < 4; mi++)
      #pragma unroll
      for (int ni = 0; ni < 4; ni++)
        acc[mi][ni] = mfma16(a[mi], bc[ni], acc[mi][ni]);
  };

  short8 bA[4], bB[4];
  stgA(0, 0); stgA(1, 1); loadB(bA, 0);
  __syncthreads();
  #pragma unroll
  for (int t = 0; t < 6; t++){
    int rb = (t & 1) * 2, sb = 2 - rb;
    if (t < 5){ stgA(sb, 2 * t + 2); stgA(sb + 1, 2 * t + 3); }
    loadB(bB, 2 * t + 1);
    compute(rb, bA);
    if (t < 5) loadB(bA, 2 * t + 2);
    compute(rb + 1, bB);
    __syncthreads();
  }

  // epilogue: bias + GELU -> wave-private LDS transpose -> 16B stores
  char* scr = (char*)stage + wid * 2304;    // 16 rows x 144B
  #pragma unroll
  for (int mi = 0; mi < 4; mi++){
    #pragma unroll
    for (int ni = 0; ni < 4; ni++){
      float fb = fc1b[col0 + wn * 64 + ni * 16 + colb];
      #pragma unroll
      for (int rr = 0; rr < 4; rr++){
        float v = acc[mi][ni][rr] + fb;
        float u = v * (1.0f + 0.044715f * v * v);
        float gl = v / (1.0f + __expf(-1.5957691216f * u));
        *(short*)(scr + (hi * 4 + rr) * 144 + (ni * 16 + colb) * 2) = fbits(gl);
      }
    }
    #pragma unroll
    for (int t = 0; t < 2; t++){
      int q = t * 64 + lane;
      int r = q >> 3, c8 = q & 7;
      short8 vv = *(const short8*)(scr + r * 144 + c8 * 16);
      *(short8*)(h + (row0 + wm * 64 + mi * 16 + r) * 1536
                 + col0 + wn * 64 + c8 * 8) = vv;
    }
  }
}

// ---- fc2: M=64 x N=384 x K=1536; depth-4 prefetch (4 K-steps/barrier) ----
// K = 48 steps = 12 iterations x 4. Full M: grid 2048.
__global__ __launch_bounds__(256, 2) void k_fc2(
    const __hip_bfloat16* __restrict__ h,      // [131072][1536]
    const __hip_bfloat16* __restrict__ wp,     // packed [48][24][64][8]
    const float* __restrict__ fc2b,
    const __hip_bfloat16* __restrict__ y,
    const float* __restrict__ g2, const float* __restrict__ b2v,
    float* __restrict__ out)
{
  __shared__ __attribute__((aligned(16))) char stage[8][4096];  // 32 KB
  __shared__ float red1[64][4], red2[64][4];
  const int tid = threadIdx.x, lane = tid & 63, wid = tid >> 6;
  const int colb = lane & 15, hi = lane >> 4;
  const size_t row0 = (size_t)blockIdx.x * 64;

  auto stgA = [&](int sb, int kc){
    gload16(h + (row0 + wid * 16 + colb) * 1536 + kc * 32 + hi * 8,
            &stage[sb][wid * 1024]);
  };
  const __hip_bfloat16* bbase = wp + ((size_t)(wid * 6) * 64 + lane) * 8;
  auto loadB = [&](short8 (&bb)[6], int kc){
    #pragma unroll
    for (int ni = 0; ni < 6; ni++)
      bb[ni] = *(const short8*)(bbase + (size_t)kc * 12288 + ni * 512);
  };

  f32x4 acc[4][6];
  #pragma unroll
  for (int mi = 0; mi < 4; mi++)
    #pragma unroll
    for (int ni = 0; ni < 6; ni++) acc[mi][ni] = (f32x4)(0.f);

  auto compute = [&](int rb, short8 (&bc)[6]){
    short8 a[4];
    #pragma unroll
    for (int mi = 0; mi < 4; mi++)
      a[mi] = *(const short8*)&stage[rb][mi * 1024 + lane * 16];
    #pragma unroll
    for (int mi = 0; mi < 4; mi++)
      #pragma unroll
      for (int ni = 0; ni < 6; ni++)
        acc[mi][ni] = mfma16(a[mi], bc[ni], acc[mi][ni]);
  };

  short8 bA[6], bB[6];
  stgA(0, 0); stgA(1, 1); stgA(2, 2); stgA(3, 3); loadB(bA, 0);
  __syncthreads();
  for (int t = 0; t < 12; t++){
    int rb = (t & 1) * 4, sb = 4 - rb;
    if (t < 11){
      stgA(sb + 0, 4 * t + 4); stgA(sb + 1, 4 * t + 5);
      stgA(sb + 2, 4 * t + 6); stgA(sb + 3, 4 * t + 7);
    }
    loadB(bB, 4 * t + 1);
    compute(rb + 0, bA);
    loadB(bA, 4 * t + 2);
    compute(rb + 1, bB);
    loadB(bB, 4 * t + 3);
    compute(rb + 2, bA);
    if (t < 11) loadB(bA, 4 * t + 4);
    compute(rb + 3, bB);
    __syncthreads();
  }

  float s1[4][4], s2[4][4];
  #pragma unroll
  for (int mi = 0; mi < 4; mi++)
    #pragma unroll
    for (int rr = 0; rr < 4; rr++){ s1[mi][rr] = 0.f; s2[mi][rr] = 0.f; }
  #pragma unroll
  for (int ni = 0; ni < 6; ni++){
    float fb = fc2b[wid * 96 + ni * 16 + colb];
    #pragma unroll
    for (int mi = 0; mi < 4; mi++)
      #pragma unroll
      for (int rr = 0; rr < 4; rr++){
        float v = acc[mi][ni][rr] + fb;
        acc[mi][ni][rr] = v;
        s1[mi][rr] += v; s2[mi][rr] += v * v;
      }
  }
  #pragma unroll
  for (int mi = 0; mi < 4; mi++)
    #pragma unroll
    for (int rr = 0; rr < 4; rr++){
      float a = wsum16(s1[mi][rr]);
      float b = wsum16(s2[mi][rr]);
      if (colb == 0){
        int row = mi * 16 + hi * 4 + rr;
        red1[row][wid] = a; red2[row][wid] = b;
      }
    }
  __syncthreads();

  #pragma unroll
  for (int mi = 0; mi < 4; mi++)
    #pragma unroll
    for (int rr = 0; rr < 4; rr++){
      int row = mi * 16 + hi * 4 + rr;
      float t1 = red1[row][0] + red1[row][1] + red1[row][2] + red1[row][3];
      float t2 = red2[row][0] + red2[row][1] + red2[row][2] + red2[row][3];
      float mean = t1 * (1.f / 384.f);
      float var  = t2 * (1.f / 384.f) - mean * mean;
      float inv  = rsqrtf(var + 1e-5f);
      size_t grow = row0 + row;
      const __hip_bfloat16* yp = y + grow * DIM;
      float* op = out + grow * DIM;
      #pragma unroll
      for (int ni = 0; ni < 6; ni++){
        int c = wid * 96 + ni * 16 + colb;
        float ln = (acc[mi][ni][rr] - mean) * inv * g2[c] + b2v[c];
        op[c] = bf2f(*(const short*)(yp + c)) + ln;
      }
    }
}

extern "C" void kernel_launch(void* const* d_in, const int* in_sizes, int n_in,
                              void* d_out, int out_size, void* d_ws, size_t ws_size,
                              hipStream_t stream)
{
  (void)in_sizes; (void)n_in; (void)out_size; (void)ws_size;
  const float* x    = (const float*)d_in[0];
  const float* qkvw_f = (const float*)d_in[3];
  const float* qkvb = (const float*)d_in[4];
  const float* lsc  = (const float*)d_in[5];
  const float* cw1  = (const float*)d_in[6];
  const float* cb1  = (const float*)d_in[7];
  const float* cw2  = (const float*)d_in[8];
  const float* pw   = (const float*)d_in[9];
  const float* pb   = (const float*)d_in[10];
  const float* g1   = (const float*)d_in[11];
  const float* b1   = (const float*)d_in[12];
  const float* g2   = (const float*)d_in[13];
  const float* b2   = (const float*)d_in[14];
  const float* f1w  = (const float*)d_in[15];
  const float* f1b  = (const float*)d_in[16];
  const float* f2w  = (const float*)d_in[17];
  const float* f2b  = (const float*)d_in[18];

  char* ws = (char*)d_ws;
  size_t off = 0;
  auto alloc = [&](size_t bytes) -> char* {
    char* p = ws + off;
    off += (bytes + 255) & ~(size_t)255;
    return p;
  };
  __hip_bfloat16* qkvp = (__hip_bfloat16*)alloc((size_t)12 * 72 * 512 * 2);
  __hip_bfloat16* projp= (__hip_bfloat16*)alloc((size_t)12 * 24 * 512 * 2);
  __hip_bfloat16* fc1p = (__hip_bfloat16*)alloc((size_t)12 * 96 * 512 * 2);
  __hip_bfloat16* fc2p = (__hip_bfloat16*)alloc((size_t)48 * 24 * 512 * 2);
  float* scalev = (float*)alloc(NH * 4);
  float* hbias  = (float*)alloc(225 * NH * 4);
  float* bias16 = (float*)alloc((size_t)NH * 64 * 64 * 4);
  __hip_bfloat16* yb    = (__hip_bfloat16*)alloc((size_t)131072 * DIM * 2);
  __hip_bfloat16* xbb   = (__hip_bfloat16*)alloc((size_t)131072 * DIM * 2);
  __hip_bfloat16* qbuf  = (__hip_bfloat16*)alloc((size_t)131072 * DIM * 2);
  __hip_bfloat16* kbuf  = (__hip_bfloat16*)alloc((size_t)131072 * DIM * 2);
  __hip_bfloat16* vTbuf = (__hip_bfloat16*)alloc((size_t)131072 * DIM * 2);
  // h [131072][1536] bf16 = 402,653,184 B overlays xbb+qbuf+kbuf+vTbuf
  __hip_bfloat16* hbuf  = xbb;

  k_pack<<<216, 256, 0, stream>>>(qkvw_f, qkvp, 1152, 384);
  k_pack<<<72, 256, 0, stream>>>(pw, projp, 384, 384);
  k_pack<<<288, 256, 0, stream>>>(f1w, fc1p, 1536, 384);
  k_pack<<<288, 256, 0, stream>>>(f2w, fc2p, 384, 1536);
  k_cpb<<<225, 256, 0, stream>>>(cw1, cb1, cw2, hbias);
  k_bias16<<<192, 256, 0, stream>>>(hbias, lsc, bias16, scalev);

  k_cast8<<<2048, 256, 0, stream>>>((const float4*)x, (short4v*)xbb,
                                    131072 * DIM / 8);
  k_qkv<<<9216, 256, 0, stream>>>(xbb, qkvp, qkvb, scalev, qbuf, kbuf, vTbuf);
  k_winproj<<<2048, 256, 0, stream>>>(qbuf, kbuf, vTbuf, bias16, projp, pb,
                                      x, g1, b1, yb);
  k_fc1<<<12288, 256, 0, stream>>>(yb, fc1p, f1b, hbuf);
  k_fc2<<<2048, 256, 0, stream>>>(hbuf, fc2p, f2b, yb, g2, b2, (float*)d_out);
}